// Round 8
// baseline (410.786 us; speedup 1.0000x reference)
//
#include <hip/hip_runtime.h>

typedef unsigned int u32;
typedef unsigned short u16;
typedef __attribute__((ext_vector_type(8))) short bf16x8;
typedef __attribute__((ext_vector_type(4))) float f32x4;

#define CAP 2560      // slots per coarse bucket (mean 2046, 11 sigma slack, guarded)
#define CHUNK 8192    // edges per bucket_count block
#define GMT 2         // row-tiles per wave in GEMM (32 rows/wave, 128 rows/block)

__device__ __forceinline__ float bfl(u32 v){ return __uint_as_float(v << 16); }
__device__ __forceinline__ float bfh(u32 v){ return __uint_as_float(v & 0xffff0000u); }
__device__ __forceinline__ u16 f2bf(float f){
    u32 u = __float_as_uint(f);
    u += 0x7fffu + ((u >> 16) & 1u);
    return (u16)(u >> 16);
}
__device__ __forceinline__ u32 pack2(float a, float b){
    u32 ua = __float_as_uint(a); ua += 0x7fffu + ((ua >> 16) & 1u);
    u32 ub = __float_as_uint(b); ub += 0x7fffu + ((ub >> 16) & 1u);
    return (ua >> 16) | (ub & 0xffff0000u);
}

// ---------------- CSR build, two-level bucketing ----------------

__global__ __launch_bounds__(256) void bucket_count(const int* __restrict__ dst,
                                                    const int* __restrict__ src,
                                                    int* __restrict__ gcur,
                                                    u32* __restrict__ slots,
                                                    int NBk, int E){
    __shared__ int cnt[800];
    int t = threadIdx.x;
    int e0 = blockIdx.x * CHUNK;
    for (int i = t; i < NBk; i += 256) cnt[i] = 0;
    __syncthreads();
    #pragma unroll
    for (int k = 0; k < CHUNK / 256; k++){
        int e = e0 + t + k * 256;
        if (e < E) atomicAdd(&cnt[dst[e] >> 7], 1);
    }
    __syncthreads();
    for (int i = t; i < NBk; i += 256){
        int c = cnt[i];
        cnt[i] = c ? atomicAdd(&gcur[i], c) : 0;
    }
    __syncthreads();
    #pragma unroll
    for (int k = 0; k < CHUNK / 256; k++){
        int e = e0 + t + k * 256;
        if (e < E){
            int d = dst[e];
            int b = d >> 7;
            int pos = atomicAdd(&cnt[b], 1);
            if (pos < CAP) slots[b * CAP + pos] = ((u32)(d & 127) << 17) | (u32)src[e];
        }
    }
}

// pass 2 (+ fused sumx/gmap): one block per bucket; stage edges in LDS,
// 128-ctr histogram + x-accumulate, wave scan -> node-grouped CSR + sval + gmap.

__global__ __launch_bounds__(256) void bucket_csr(const int* __restrict__ gcur,
                                                  u32* __restrict__ csr,
                                                  int* __restrict__ starts,
                                                  int* __restrict__ ends,
                                                  const float* __restrict__ x,
                                                  const int* __restrict__ n2s,
                                                  const int* __restrict__ s2g,
                                                  float* __restrict__ sval,
                                                  int* __restrict__ gmap, int N){
    __shared__ u32 ebuf[CAP];
    __shared__ int cnt[128], excl[128], cur[128];
    __shared__ float sacc[128];
    int b = blockIdx.x, t = threadIdx.x;
    int base = b * CAP;
    int sz = gcur[b]; if (sz > CAP) sz = CAP;
    if (t < 128){ cnt[t] = 0; sacc[t] = 0.f; }
    __syncthreads();
    for (int i = t; i < sz; i += 256){
        u32 p = csr[base + i];
        ebuf[i] = p;
        atomicAdd(&cnt[p >> 17], 1);
        atomicAdd(&sacc[p >> 17], x[p & 0x1FFFFu]);
    }
    __syncthreads();
    if (t < 64){
        int c0 = cnt[2 * t], c1 = cnt[2 * t + 1];
        int tot = c0 + c1;
        int incl = tot;
        #pragma unroll
        for (int o = 1; o < 64; o <<= 1){
            int v = __shfl_up(incl, o);
            if (t >= o) incl += v;
        }
        int ex = incl - tot;
        excl[2 * t] = ex;
        excl[2 * t + 1] = ex + c0;
    }
    __syncthreads();
    if (t < 128){
        int node = b * 128 + t;
        if (node < N){
            int st = base + excl[t];
            starts[node] = st;
            ends[node] = st + cnt[t];
            sval[node] = x[node] + sacc[t];
            gmap[node] = s2g[n2s[node]];
        }
        cur[t] = excl[t];
    }
    __syncthreads();
    for (int i = t; i < sz; i += 256){
        u32 p = ebuf[i];
        int dl = p >> 17;
        int r = atomicAdd(&cur[dl], 1);
        csr[base + r] = p & 0x1FFFFu;
    }
}

// ---------------- weight pre-pack (+ workspace zeroing in blocks 5/6) ----------------
// f32 W[k][n] -> bf16 WT[n][k], XOR-swizzled 16B chunks; swizzle index = (n>>3)&15.

struct W5 { const float* p[5]; };

__global__ void pack_k(W5 w5, u16* __restrict__ wp,
                       int* __restrict__ gcur, int ngcur,
                       float* __restrict__ outz, int nout){
    int m = blockIdx.x;
    int t = threadIdx.x;
    if (m == 5){
        for (int i = t; i < ngcur; i += 256) gcur[i] = 0;
        return;
    }
    if (m == 6){
        for (int i = t; i < nout; i += 256) outz[i] = 0.f;
        return;
    }
    const float* W = w5.p[m];
    u16* dstp = wp + m * 16384;
    #pragma unroll
    for (int it = 0; it < 8; it++){
        int task = t + 256 * it;         // 2048 chunks: (n, c)
        int n = task & 127, c = task >> 7;
        u16 tmp[8];
        #pragma unroll
        for (int j = 0; j < 8; j++) tmp[j] = f2bf(W[(c * 8 + j) * 128 + n]);
        uint4 val;
        val.x = (u32)tmp[0] | ((u32)tmp[1] << 16);
        val.y = (u32)tmp[2] | ((u32)tmp[3] << 16);
        val.z = (u32)tmp[4] | ((u32)tmp[5] << 16);
        val.w = (u32)tmp[6] | ((u32)tmp[7] << 16);
        *(uint4*)(dstp + n * 128 + ((c ^ ((n >> 3) & 15)) << 3)) = val;
    }
}

// ---------------- fused layer1 + GEMM1: A row = relu(sval[r]*W1 + b1) generated on the fly ----------------

__global__ __launch_bounds__(256) void gemm1_fused(const float* __restrict__ sval,
                                                   const float* __restrict__ W1,
                                                   const float* __restrict__ b1,
                                                   const u16* __restrict__ Wp,
                                                   const float* __restrict__ bias,
                                                   u16* __restrict__ Out, int nrows){
    __shared__ uint4 ldsbuf[2048];          // 32 KB swizzled WT bf16
    __shared__ float w1s[128], b1s[128];
    u16* lds = (u16*)ldsbuf;
    int t = threadIdx.x;
    const uint4* wsrc = (const uint4*)Wp;
    #pragma unroll
    for (int j = 0; j < 8; j++) ldsbuf[t + 256 * j] = wsrc[t + 256 * j];
    if (t < 128){ w1s[t] = W1[t]; b1s[t] = b1[t]; }
    __syncthreads();

    int wave = t >> 6, lane = t & 63;
    int m = lane & 15, q = lane >> 4;
    int r0 = blockIdx.x * (64 * GMT) + wave * (16 * GMT);

    float sv[GMT];
    #pragma unroll
    for (int mt = 0; mt < GMT; mt++){
        int row = r0 + mt * 16 + m;
        if (row >= nrows) row = nrows - 1;
        sv[mt] = sval[row];
    }

    f32x4 acc[GMT][8];
    #pragma unroll
    for (int a = 0; a < GMT; a++)
        #pragma unroll
        for (int b = 0; b < 8; b++){ f32x4 z = {0.f, 0.f, 0.f, 0.f}; acc[a][b] = z; }

    #pragma unroll
    for (int kt = 0; kt < 4; kt++){
        int c = kt * 4 + q;
        int k0 = kt * 32 + q * 8;
        float wk[8], bk[8];
        #pragma unroll
        for (int j = 0; j < 8; j++){ wk[j] = w1s[k0 + j]; bk[j] = b1s[k0 + j]; }
        bf16x8 bfrag[8];
        #pragma unroll
        for (int nt = 0; nt < 8; nt++){
            int n = m * 8 + nt;
            bfrag[nt] = *(const bf16x8*)(lds + n * 128 + ((c ^ m) << 3));
        }
        #pragma unroll
        for (int mt = 0; mt < GMT; mt++){
            bf16x8 afrag;
            #pragma unroll
            for (int j = 0; j < 8; j++){
                float v = sv[mt] * wk[j] + bk[j];
                v = v > 0.f ? v : 0.f;
                afrag[j] = (short)f2bf(v);
            }
            #pragma unroll
            for (int nt = 0; nt < 8; nt++)
                acc[mt][nt] = __builtin_amdgcn_mfma_f32_16x16x32_bf16(afrag, bfrag[nt], acc[mt][nt], 0, 0, 0);
        }
    }

    float4 bb0 = *(const float4*)(bias + m * 8);
    float4 bb1 = *(const float4*)(bias + m * 8 + 4);
    float bb[8] = {bb0.x, bb0.y, bb0.z, bb0.w, bb1.x, bb1.y, bb1.z, bb1.w};
    #pragma unroll
    for (int mt = 0; mt < GMT; mt++){
        #pragma unroll
        for (int r = 0; r < 4; r++){
            int row = r0 + mt * 16 + q * 4 + r;
            if (row < nrows){
                float v[8];
                #pragma unroll
                for (int j = 0; j < 8; j++){
                    float vv = acc[mt][j][r] + bb[j];
                    v[j] = vv > 0.f ? vv : 0.f;
                }
                uint4 o;
                o.x = pack2(v[0], v[1]);
                o.y = pack2(v[2], v[3]);
                o.z = pack2(v[4], v[5]);
                o.w = pack2(v[6], v[7]);
                *(uint4*)(Out + row * 128 + m * 8) = o;
            }
        }
    }
}

// ---------------- fused agg + double GEMM: Out = relu(relu((A+sumA)@W1+b1)@W2+b2) ----------------
// Phase A: gather-aggregate 128 rows into a 32 KB XOR-swizzled LDS tile (bf16).
// Phases B/C: MFMA with B-fragments read directly from packed global W (L1/L2-resident).
// Only 32 KB LDS/block -> ~4 blocks/CU; resident blocks de-phase so the gather
// fabric queue stays full while other blocks run MFMA.

__device__ __forceinline__ void acc8(float* a, uint4 u){
    a[0] += bfl(u.x); a[1] += bfh(u.x);
    a[2] += bfl(u.y); a[3] += bfh(u.y);
    a[4] += bfl(u.z); a[5] += bfh(u.z);
    a[6] += bfl(u.w); a[7] += bfh(u.w);
}

__global__ __launch_bounds__(256) void agg_mlp_fused(const uint4* __restrict__ Hin,
                                                     const u16* __restrict__ Wp1,
                                                     const u16* __restrict__ Wp2,
                                                     const float* __restrict__ bias1,
                                                     const float* __restrict__ bias2,
                                                     const int* __restrict__ starts,
                                                     const int* __restrict__ ends,
                                                     const u32* __restrict__ csr,
                                                     u16* __restrict__ Out, int nrows){
    __shared__ uint4 hbuf[2048];        // 32 KB: aggregated A-tile, then h-tile
    u16* lds = (u16*)hbuf;
    int t = threadIdx.x;
    int r0blk = blockIdx.x * 128;

    // ---- phase A: aggregate 128 rows into LDS ----
    {
        int gi = t >> 4;        // 16 node-groups of 16 lanes
        int c = t & 15;
        #pragma unroll
        for (int it = 0; it < 8; it++){
            int rl = it * 16 + gi;
            int node = r0blk + rl;
            if (node < nrows){
                uint4 v = Hin[node * 16 + c];
                float a[8];
                a[0] = bfl(v.x); a[1] = bfh(v.x);
                a[2] = bfl(v.y); a[3] = bfh(v.y);
                a[4] = bfl(v.z); a[5] = bfh(v.z);
                a[6] = bfl(v.w); a[7] = bfh(v.w);
                int b0 = starts[node], b1 = ends[node];
                int j = b0;
                for (; j + 4 <= b1; j += 4){
                    int s0 = csr[j], s1 = csr[j + 1], s2 = csr[j + 2], s3 = csr[j + 3];
                    uint4 u0 = Hin[s0 * 16 + c];
                    uint4 u1 = Hin[s1 * 16 + c];
                    uint4 u2 = Hin[s2 * 16 + c];
                    uint4 u3 = Hin[s3 * 16 + c];
                    acc8(a, u0); acc8(a, u1); acc8(a, u2); acc8(a, u3);
                }
                for (; j < b1; j++){
                    uint4 u = Hin[csr[j] * 16 + c];
                    acc8(a, u);
                }
                uint4 o;
                o.x = pack2(a[0], a[1]);
                o.y = pack2(a[2], a[3]);
                o.z = pack2(a[4], a[5]);
                o.w = pack2(a[6], a[7]);
                *(uint4*)(lds + rl * 128 + ((c ^ (rl & 15)) << 3)) = o;
            }
        }
    }
    __syncthreads();

    int wave = t >> 6, lane = t & 63;
    int m = lane & 15, q = lane >> 4;
    int rl0 = wave * (16 * GMT);
    int r0 = r0blk + rl0;

    f32x4 acc[GMT][8];
    #pragma unroll
    for (int a = 0; a < GMT; a++)
        #pragma unroll
        for (int b = 0; b < 8; b++){ f32x4 z = {0.f, 0.f, 0.f, 0.f}; acc[a][b] = z; }

    // ---- phase B: A @ W1 (bfrag from global packed W1) ----
    #pragma unroll
    for (int kt = 0; kt < 4; kt++){
        int c = kt * 4 + q;
        bf16x8 bfrag[8];
        #pragma unroll
        for (int nt = 0; nt < 8; nt++){
            int n = m * 8 + nt;
            bfrag[nt] = *(const bf16x8*)(Wp1 + n * 128 + ((c ^ m) << 3));
        }
        #pragma unroll
        for (int mt = 0; mt < GMT; mt++){
            int rl = rl0 + mt * 16 + m;
            bf16x8 afrag = *(const bf16x8*)(lds + rl * 128 + ((c ^ (rl & 15)) << 3));
            #pragma unroll
            for (int nt = 0; nt < 8; nt++)
                acc[mt][nt] = __builtin_amdgcn_mfma_f32_16x16x32_bf16(afrag, bfrag[nt], acc[mt][nt], 0, 0, 0);
        }
    }
    __syncthreads();               // all waves done reading the A-tile

    // ---- h -> LDS (overwrites A-tile) ----
    {
        float4 bb0 = *(const float4*)(bias1 + m * 8);
        float4 bb1 = *(const float4*)(bias1 + m * 8 + 4);
        float bb[8] = {bb0.x, bb0.y, bb0.z, bb0.w, bb1.x, bb1.y, bb1.z, bb1.w};
        #pragma unroll
        for (int mt = 0; mt < GMT; mt++){
            #pragma unroll
            for (int r = 0; r < 4; r++){
                int rl = rl0 + mt * 16 + q * 4 + r;
                float v[8];
                #pragma unroll
                for (int j = 0; j < 8; j++){
                    float vv = acc[mt][j][r] + bb[j];
                    v[j] = vv > 0.f ? vv : 0.f;
                }
                uint4 o;
                o.x = pack2(v[0], v[1]);
                o.y = pack2(v[2], v[3]);
                o.z = pack2(v[4], v[5]);
                o.w = pack2(v[6], v[7]);
                *(uint4*)(lds + rl * 128 + ((m ^ (rl & 15)) << 3)) = o;
            }
        }
    }
    __syncthreads();

    // ---- phase C: h @ W2 (bfrag from global packed W2) ----
    #pragma unroll
    for (int a = 0; a < GMT; a++)
        #pragma unroll
        for (int b = 0; b < 8; b++){ f32x4 z = {0.f, 0.f, 0.f, 0.f}; acc[a][b] = z; }

    #pragma unroll
    for (int kt = 0; kt < 4; kt++){
        int c = kt * 4 + q;
        bf16x8 bfrag[8];
        #pragma unroll
        for (int nt = 0; nt < 8; nt++){
            int n = m * 8 + nt;
            bfrag[nt] = *(const bf16x8*)(Wp2 + n * 128 + ((c ^ m) << 3));
        }
        #pragma unroll
        for (int mt = 0; mt < GMT; mt++){
            int rl = rl0 + mt * 16 + m;
            bf16x8 afrag = *(const bf16x8*)(lds + rl * 128 + ((c ^ (rl & 15)) << 3));
            #pragma unroll
            for (int nt = 0; nt < 8; nt++)
                acc[mt][nt] = __builtin_amdgcn_mfma_f32_16x16x32_bf16(afrag, bfrag[nt], acc[mt][nt], 0, 0, 0);
        }
    }

    float4 bb0 = *(const float4*)(bias2 + m * 8);
    float4 bb1 = *(const float4*)(bias2 + m * 8 + 4);
    float bb[8] = {bb0.x, bb0.y, bb0.z, bb0.w, bb1.x, bb1.y, bb1.z, bb1.w};
    #pragma unroll
    for (int mt = 0; mt < GMT; mt++){
        #pragma unroll
        for (int r = 0; r < 4; r++){
            int row = r0 + mt * 16 + q * 4 + r;
            if (row < nrows){
                float v[8];
                #pragma unroll
                for (int j = 0; j < 8; j++){
                    float vv = acc[mt][j][r] + bb[j];
                    v[j] = vv > 0.f ? vv : 0.f;
                }
                uint4 o;
                o.x = pack2(v[0], v[1]);
                o.y = pack2(v[2], v[3]);
                o.z = pack2(v[4], v[5]);
                o.w = pack2(v[6], v[7]);
                *(uint4*)(Out + row * 128 + m * 8) = o;
            }
        }
    }
}

// ---------------- pooling: 64-row segments per wave, gmap precomputed, run-flush atomics ----------------

__global__ __launch_bounds__(256) void pool2_k(const u32* __restrict__ H,
                                               const int* __restrict__ gmap,
                                               float* __restrict__ out, int N){
    int c = threadIdx.x & 63;        // column pair: cols 2c, 2c+1
    int seg = blockIdx.x * 4 + (threadIdx.x >> 6);
    int start = seg * 64;
    if (start >= N) return;
    int end = start + 64; if (end > N) end = N;
    int g = gmap[start];
    float a0 = 0.f, a1 = 0.f;
    for (int n = start; n < end; n++){
        int gn = gmap[n];
        if (gn != g){
            unsafeAtomicAdd(&out[g * 128 + 2 * c], a0);
            unsafeAtomicAdd(&out[g * 128 + 2 * c + 1], a1);
            a0 = 0.f; a1 = 0.f; g = gn;
        }
        u32 u = H[n * 64 + c];
        a0 += bfl(u);
        a1 += bfh(u);
    }
    unsafeAtomicAdd(&out[g * 128 + 2 * c], a0);
    unsafeAtomicAdd(&out[g * 128 + 2 * c + 1], a1);
}

extern "C" void kernel_launch(void* const* d_in, const int* in_sizes, int n_in,
                              void* d_out, int out_size, void* d_ws, size_t ws_size,
                              hipStream_t stream){
    const float* x    = (const float*)d_in[0];
    const int*   ei   = (const int*)d_in[1];
    const int*   n2s  = (const int*)d_in[2];
    const int*   s2g  = (const int*)d_in[3];
    const float* c1W1 = (const float*)d_in[4];
    const float* c1b1 = (const float*)d_in[5];
    const float* c1W2 = (const float*)d_in[6];
    const float* c1b2 = (const float*)d_in[7];
    const float* cW1  = (const float*)d_in[8];
    const float* cb1  = (const float*)d_in[9];
    const float* cW2  = (const float*)d_in[10];
    const float* cb2  = (const float*)d_in[11];
    float* out = (float*)d_out;

    int N = in_sizes[0];          // 100000
    int E = in_sizes[1] / 2;      // 1600000
    const int* src = ei;
    const int* dst = ei + E;
    int NBk = (N + 127) / 128;    // 782 coarse buckets

    // ---- workspace layout ----
    char* w = (char*)d_ws;
    size_t off = 0;
    auto al = [&](size_t b){ size_t r = off; off += (b + 255) & ~(size_t)255; return r; };
    int*   gcur   = (int*)(w + al((size_t)NBk * 4));
    int*   starts = (int*)(w + al((size_t)N * 4));
    int*   ends   = (int*)(w + al((size_t)N * 4));
    float* sval   = (float*)(w + al((size_t)N * 4));
    int*   gmap   = (int*)(w + al((size_t)N * 4));
    u32*   csr    = (u32*)(w + al((size_t)NBk * CAP * 4));
    u16*   wp     = (u16*)(w + al((size_t)5 * 16384 * 2));
    u16*   P      = (u16*)(w + al((size_t)N * 128 * 2));
    u16*   Q      = (u16*)(w + al((size_t)N * 128 * 2));

    // pack 5 weight matrices; blocks 5/6 zero gcur and out
    W5 w5;
    w5.p[0] = c1W2;
    w5.p[1] = cW1;           // layer2 W1
    w5.p[2] = cW2;           // layer2 W2
    w5.p[3] = cW1 + 16384;   // layer3 W1
    w5.p[4] = cW2 + 16384;   // layer3 W2
    pack_k<<<7, 256, 0, stream>>>(w5, wp, gcur, NBk, out, out_size);

    // CSR build (+ fused sval/gmap)
    bucket_count<<<(E + CHUNK - 1) / CHUNK, 256, 0, stream>>>(dst, src, gcur, csr, NBk, E);
    bucket_csr<<<NBk, 256, 0, stream>>>(gcur, csr, starts, ends, x, n2s, s2g, sval, gmap, N);

    int gG = (N + 64 * GMT - 1) / (64 * GMT);   // 128 rows per block
    // layer 1 (fused: h=relu(sval*W1+b1) generated in-kernel, then @W2)
    gemm1_fused<<<gG, 256, 0, stream>>>(sval, c1W1, c1b1, wp + 0 * 16384, c1b2, P, N);
    // layer 2: fused agg + MLP, P -> Q
    agg_mlp_fused<<<gG, 256, 0, stream>>>((const uint4*)P, wp + 1 * 16384, wp + 2 * 16384,
                                          cb1, cb2, starts, ends, csr, Q, N);
    // layer 3: fused agg + MLP, Q -> P
    agg_mlp_fused<<<gG, 256, 0, stream>>>((const uint4*)Q, wp + 3 * 16384, wp + 4 * 16384,
                                          cb1 + 128, cb2 + 128, starts, ends, csr, P, N);
    // pooling
    pool2_k<<<(N + 255) / 256, 256, 0, stream>>>((const u32*)P, gmap, out, N);
}

// Round 9
// 322.408 us; speedup vs baseline: 1.2741x; 1.2741x over previous
//
#include <hip/hip_runtime.h>

typedef unsigned int u32;
typedef unsigned short u16;
typedef __attribute__((ext_vector_type(8))) short bf16x8;
typedef __attribute__((ext_vector_type(4))) float f32x4;

#define CAP 2560      // slots per coarse bucket (mean 2046, 11 sigma slack, guarded)
#define CHUNK 8192    // edges per bucket_count block
#define GMT 2         // row-tiles per wave in GEMM (32 rows/wave, 128 rows/block)

__device__ __forceinline__ float bfl(u32 v){ return __uint_as_float(v << 16); }
__device__ __forceinline__ float bfh(u32 v){ return __uint_as_float(v & 0xffff0000u); }
__device__ __forceinline__ u16 f2bf(float f){
    u32 u = __float_as_uint(f);
    u += 0x7fffu + ((u >> 16) & 1u);
    return (u16)(u >> 16);
}
__device__ __forceinline__ u32 pack2(float a, float b){
    u32 ua = __float_as_uint(a); ua += 0x7fffu + ((ua >> 16) & 1u);
    u32 ub = __float_as_uint(b); ub += 0x7fffu + ((ub >> 16) & 1u);
    return (ua >> 16) | (ub & 0xffff0000u);
}

// ---------------- CSR build, two-level bucketing ----------------
// 1024 threads/block: 4x the waves of the 256-thread version -> hides the
// LDS-atomic and global-atomic latency (grid is only ~196 blocks, <1 per CU).

__global__ __launch_bounds__(1024) void bucket_count(const int* __restrict__ dst,
                                                     const int* __restrict__ src,
                                                     int* __restrict__ gcur,
                                                     u32* __restrict__ slots,
                                                     int NBk, int E){
    __shared__ int cnt[800];
    int t = threadIdx.x;
    int e0 = blockIdx.x * CHUNK;
    for (int i = t; i < NBk; i += 1024) cnt[i] = 0;
    __syncthreads();
    #pragma unroll
    for (int k = 0; k < CHUNK / 1024; k++){
        int e = e0 + t + k * 1024;
        if (e < E) atomicAdd(&cnt[dst[e] >> 7], 1);
    }
    __syncthreads();
    for (int i = t; i < NBk; i += 1024){
        int c = cnt[i];
        cnt[i] = c ? atomicAdd(&gcur[i], c) : 0;
    }
    __syncthreads();
    #pragma unroll
    for (int k = 0; k < CHUNK / 1024; k++){
        int e = e0 + t + k * 1024;
        if (e < E){
            int d = dst[e];
            int b = d >> 7;
            int pos = atomicAdd(&cnt[b], 1);
            if (pos < CAP) slots[b * CAP + pos] = ((u32)(d & 127) << 17) | (u32)src[e];
        }
    }
}

// pass 2 (+ fused sumx/gmap): one block per bucket; stage edges in LDS,
// 128-ctr histogram + x-accumulate, wave scan -> node-grouped CSR + sval + gmap.

__global__ __launch_bounds__(512) void bucket_csr(const int* __restrict__ gcur,
                                                  u32* __restrict__ csr,
                                                  int* __restrict__ starts,
                                                  int* __restrict__ ends,
                                                  const float* __restrict__ x,
                                                  const int* __restrict__ n2s,
                                                  const int* __restrict__ s2g,
                                                  float* __restrict__ sval,
                                                  int* __restrict__ gmap, int N){
    __shared__ u32 ebuf[CAP];
    __shared__ int cnt[128], excl[128], cur[128];
    __shared__ float sacc[128];
    int b = blockIdx.x, t = threadIdx.x;
    int base = b * CAP;
    int sz = gcur[b]; if (sz > CAP) sz = CAP;
    if (t < 128){ cnt[t] = 0; sacc[t] = 0.f; }
    __syncthreads();
    for (int i = t; i < sz; i += 512){
        u32 p = csr[base + i];
        ebuf[i] = p;
        atomicAdd(&cnt[p >> 17], 1);
        atomicAdd(&sacc[p >> 17], x[p & 0x1FFFFu]);
    }
    __syncthreads();
    if (t < 64){
        int c0 = cnt[2 * t], c1 = cnt[2 * t + 1];
        int tot = c0 + c1;
        int incl = tot;
        #pragma unroll
        for (int o = 1; o < 64; o <<= 1){
            int v = __shfl_up(incl, o);
            if (t >= o) incl += v;
        }
        int ex = incl - tot;
        excl[2 * t] = ex;
        excl[2 * t + 1] = ex + c0;
    }
    __syncthreads();
    if (t < 128){
        int node = b * 128 + t;
        if (node < N){
            int st = base + excl[t];
            starts[node] = st;
            ends[node] = st + cnt[t];
            sval[node] = x[node] + sacc[t];
            gmap[node] = s2g[n2s[node]];
        }
        cur[t] = excl[t];
    }
    __syncthreads();
    for (int i = t; i < sz; i += 512){
        u32 p = ebuf[i];
        int dl = p >> 17;
        int r = atomicAdd(&cur[dl], 1);
        csr[base + r] = p & 0x1FFFFu;
    }
}

// ---------------- weight pre-pack (+ workspace zeroing in blocks 5/6) ----------------
// f32 W[k][n] -> bf16 WT[n][k], XOR-swizzled 16B chunks; swizzle index = (n>>3)&15.

struct W5 { const float* p[5]; };

__global__ void pack_k(W5 w5, u16* __restrict__ wp,
                       int* __restrict__ gcur, int ngcur,
                       float* __restrict__ outz, int nout){
    int m = blockIdx.x;
    int t = threadIdx.x;
    if (m == 5){
        for (int i = t; i < ngcur; i += 256) gcur[i] = 0;
        return;
    }
    if (m == 6){
        for (int i = t; i < nout; i += 256) outz[i] = 0.f;
        return;
    }
    const float* W = w5.p[m];
    u16* dstp = wp + m * 16384;
    #pragma unroll
    for (int it = 0; it < 8; it++){
        int task = t + 256 * it;         // 2048 chunks: (n, c)
        int n = task & 127, c = task >> 7;
        u16 tmp[8];
        #pragma unroll
        for (int j = 0; j < 8; j++) tmp[j] = f2bf(W[(c * 8 + j) * 128 + n]);
        uint4 val;
        val.x = (u32)tmp[0] | ((u32)tmp[1] << 16);
        val.y = (u32)tmp[2] | ((u32)tmp[3] << 16);
        val.z = (u32)tmp[4] | ((u32)tmp[5] << 16);
        val.w = (u32)tmp[6] | ((u32)tmp[7] << 16);
        *(uint4*)(dstp + n * 128 + ((c ^ ((n >> 3) & 15)) << 3)) = val;
    }
}

// ---------------- fused layer1 + GEMM1: A row = relu(sval[r]*W1 + b1) generated on the fly ----------------

__global__ __launch_bounds__(256) void gemm1_fused(const float* __restrict__ sval,
                                                   const float* __restrict__ W1,
                                                   const float* __restrict__ b1,
                                                   const u16* __restrict__ Wp,
                                                   const float* __restrict__ bias,
                                                   u16* __restrict__ Out, int nrows){
    __shared__ uint4 ldsbuf[2048];          // 32 KB swizzled WT bf16
    __shared__ float w1s[128], b1s[128];
    u16* lds = (u16*)ldsbuf;
    int t = threadIdx.x;
    const uint4* wsrc = (const uint4*)Wp;
    #pragma unroll
    for (int j = 0; j < 8; j++) ldsbuf[t + 256 * j] = wsrc[t + 256 * j];
    if (t < 128){ w1s[t] = W1[t]; b1s[t] = b1[t]; }
    __syncthreads();

    int wave = t >> 6, lane = t & 63;
    int m = lane & 15, q = lane >> 4;
    int r0 = blockIdx.x * (64 * GMT) + wave * (16 * GMT);

    float sv[GMT];
    #pragma unroll
    for (int mt = 0; mt < GMT; mt++){
        int row = r0 + mt * 16 + m;
        if (row >= nrows) row = nrows - 1;
        sv[mt] = sval[row];
    }

    f32x4 acc[GMT][8];
    #pragma unroll
    for (int a = 0; a < GMT; a++)
        #pragma unroll
        for (int b = 0; b < 8; b++){ f32x4 z = {0.f, 0.f, 0.f, 0.f}; acc[a][b] = z; }

    #pragma unroll
    for (int kt = 0; kt < 4; kt++){
        int c = kt * 4 + q;
        int k0 = kt * 32 + q * 8;
        float wk[8], bk[8];
        #pragma unroll
        for (int j = 0; j < 8; j++){ wk[j] = w1s[k0 + j]; bk[j] = b1s[k0 + j]; }
        bf16x8 bfrag[8];
        #pragma unroll
        for (int nt = 0; nt < 8; nt++){
            int n = m * 8 + nt;
            bfrag[nt] = *(const bf16x8*)(lds + n * 128 + ((c ^ m) << 3));
        }
        #pragma unroll
        for (int mt = 0; mt < GMT; mt++){
            bf16x8 afrag;
            #pragma unroll
            for (int j = 0; j < 8; j++){
                float v = sv[mt] * wk[j] + bk[j];
                v = v > 0.f ? v : 0.f;
                afrag[j] = (short)f2bf(v);
            }
            #pragma unroll
            for (int nt = 0; nt < 8; nt++)
                acc[mt][nt] = __builtin_amdgcn_mfma_f32_16x16x32_bf16(afrag, bfrag[nt], acc[mt][nt], 0, 0, 0);
        }
    }

    float4 bb0 = *(const float4*)(bias + m * 8);
    float4 bb1 = *(const float4*)(bias + m * 8 + 4);
    float bb[8] = {bb0.x, bb0.y, bb0.z, bb0.w, bb1.x, bb1.y, bb1.z, bb1.w};
    #pragma unroll
    for (int mt = 0; mt < GMT; mt++){
        #pragma unroll
        for (int r = 0; r < 4; r++){
            int row = r0 + mt * 16 + q * 4 + r;
            if (row < nrows){
                float v[8];
                #pragma unroll
                for (int j = 0; j < 8; j++){
                    float vv = acc[mt][j][r] + bb[j];
                    v[j] = vv > 0.f ? vv : 0.f;
                }
                uint4 o;
                o.x = pack2(v[0], v[1]);
                o.y = pack2(v[2], v[3]);
                o.z = pack2(v[4], v[5]);
                o.w = pack2(v[6], v[7]);
                *(uint4*)(Out + row * 128 + m * 8) = o;
            }
        }
    }
}

// ---------------- fused double GEMM: Out = relu(relu(A@W1+b1)@W2+b2) ----------------
// h kept in LDS (XOR-swizzled by row), overwriting W1's buffer after a barrier.

__global__ __launch_bounds__(256) void gemm2_fused(const u16* A,
                                                   const u16* __restrict__ Wp1,
                                                   const u16* __restrict__ Wp2,
                                                   const float* __restrict__ bias1,
                                                   const float* __restrict__ bias2,
                                                   u16* Out, int nrows){
    __shared__ uint4 buf1[2048];   // W1 (32 KB), later h
    __shared__ uint4 buf2[2048];   // W2 (32 KB)
    u16* lds1 = (u16*)buf1;
    u16* lds2 = (u16*)buf2;
    int t = threadIdx.x;
    #pragma unroll
    for (int j = 0; j < 8; j++){
        buf1[t + 256 * j] = ((const uint4*)Wp1)[t + 256 * j];
        buf2[t + 256 * j] = ((const uint4*)Wp2)[t + 256 * j];
    }
    __syncthreads();

    int wave = t >> 6, lane = t & 63;
    int m = lane & 15, q = lane >> 4;
    int rl0 = wave * (16 * GMT);                       // local row base of this wave
    int r0 = blockIdx.x * (64 * GMT) + rl0;

    f32x4 acc[GMT][8];
    #pragma unroll
    for (int a = 0; a < GMT; a++)
        #pragma unroll
        for (int b = 0; b < 8; b++){ f32x4 z = {0.f, 0.f, 0.f, 0.f}; acc[a][b] = z; }

    // ---- phase 1: A @ W1 ----
    #pragma unroll
    for (int kt = 0; kt < 4; kt++){
        int c = kt * 4 + q;
        bf16x8 bfrag[8];
        #pragma unroll
        for (int nt = 0; nt < 8; nt++){
            int n = m * 8 + nt;
            bfrag[nt] = *(const bf16x8*)(lds1 + n * 128 + ((c ^ m) << 3));
        }
        #pragma unroll
        for (int mt = 0; mt < GMT; mt++){
            int row = r0 + mt * 16 + m;
            if (row >= nrows) row = nrows - 1;
            bf16x8 afrag = *(const bf16x8*)(A + row * 128 + kt * 32 + q * 8);
            #pragma unroll
            for (int nt = 0; nt < 8; nt++)
                acc[mt][nt] = __builtin_amdgcn_mfma_f32_16x16x32_bf16(afrag, bfrag[nt], acc[mt][nt], 0, 0, 0);
        }
    }
    __syncthreads();               // all waves done reading W1

    // ---- h -> LDS (overwrites W1 buffer); chunk (row, c=m) at row*128 + ((m ^ (row&15))<<3)
    {
        float4 bb0 = *(const float4*)(bias1 + m * 8);
        float4 bb1 = *(const float4*)(bias1 + m * 8 + 4);
        float bb[8] = {bb0.x, bb0.y, bb0.z, bb0.w, bb1.x, bb1.y, bb1.z, bb1.w};
        #pragma unroll
        for (int mt = 0; mt < GMT; mt++){
            #pragma unroll
            for (int r = 0; r < 4; r++){
                int rl = rl0 + mt * 16 + q * 4 + r;
                float v[8];
                #pragma unroll
                for (int j = 0; j < 8; j++){
                    float vv = acc[mt][j][r] + bb[j];
                    v[j] = vv > 0.f ? vv : 0.f;
                }
                uint4 o;
                o.x = pack2(v[0], v[1]);
                o.y = pack2(v[2], v[3]);
                o.z = pack2(v[4], v[5]);
                o.w = pack2(v[6], v[7]);
                *(uint4*)(lds1 + rl * 128 + ((m ^ (rl & 15)) << 3)) = o;
            }
        }
    }
    __syncthreads();

    // ---- phase 2: h @ W2 ----
    #pragma unroll
    for (int a = 0; a < GMT; a++)
        #pragma unroll
        for (int b = 0; b < 8; b++){ f32x4 z = {0.f, 0.f, 0.f, 0.f}; acc[a][b] = z; }

    #pragma unroll
    for (int kt = 0; kt < 4; kt++){
        int c = kt * 4 + q;
        bf16x8 bfrag[8];
        #pragma unroll
        for (int nt = 0; nt < 8; nt++){
            int n = m * 8 + nt;
            bfrag[nt] = *(const bf16x8*)(lds2 + n * 128 + ((c ^ m) << 3));
        }
        #pragma unroll
        for (int mt = 0; mt < GMT; mt++){
            int rl = rl0 + mt * 16 + m;
            bf16x8 afrag = *(const bf16x8*)(lds1 + rl * 128 + (((kt * 4 + q) ^ (rl & 15)) << 3));
            #pragma unroll
            for (int nt = 0; nt < 8; nt++)
                acc[mt][nt] = __builtin_amdgcn_mfma_f32_16x16x32_bf16(afrag, bfrag[nt], acc[mt][nt], 0, 0, 0);
        }
    }

    float4 bb0 = *(const float4*)(bias2 + m * 8);
    float4 bb1 = *(const float4*)(bias2 + m * 8 + 4);
    float bb[8] = {bb0.x, bb0.y, bb0.z, bb0.w, bb1.x, bb1.y, bb1.z, bb1.w};
    #pragma unroll
    for (int mt = 0; mt < GMT; mt++){
        #pragma unroll
        for (int r = 0; r < 4; r++){
            int row = r0 + mt * 16 + q * 4 + r;
            if (row < nrows){
                float v[8];
                #pragma unroll
                for (int j = 0; j < 8; j++){
                    float vv = acc[mt][j][r] + bb[j];
                    v[j] = vv > 0.f ? vv : 0.f;
                }
                uint4 o;
                o.x = pack2(v[0], v[1]);
                o.y = pack2(v[2], v[3]);
                o.z = pack2(v[4], v[5]);
                o.w = pack2(v[6], v[7]);
                *(uint4*)(Out + row * 128 + m * 8) = o;
            }
        }
    }
}

// ---------------- aggregation: 16 lanes/node, 4 chains/wave, 4x unroll ----------------

__device__ __forceinline__ void acc8(float* a, uint4 u){
    a[0] += bfl(u.x); a[1] += bfh(u.x);
    a[2] += bfl(u.y); a[3] += bfh(u.y);
    a[4] += bfl(u.z); a[5] += bfh(u.z);
    a[6] += bfl(u.w); a[7] += bfh(u.w);
}

__global__ __launch_bounds__(256) void agg_k(const uint4* __restrict__ Hin, uint4* __restrict__ Hout,
                                             const int* __restrict__ starts, const int* __restrict__ ends,
                                             const u32* __restrict__ csr, int N){
    int gtid = blockIdx.x * 256 + threadIdx.x;
    int node = gtid >> 4;          // 16 lanes per node
    int c = threadIdx.x & 15;      // col quad: 8 cols (16 B)
    if (node >= N) return;

    uint4 v = Hin[node * 16 + c];
    float a[8];
    a[0] = bfl(v.x); a[1] = bfh(v.x);
    a[2] = bfl(v.y); a[3] = bfh(v.y);
    a[4] = bfl(v.z); a[5] = bfh(v.z);
    a[6] = bfl(v.w); a[7] = bfh(v.w);

    int b0 = starts[node], b1 = ends[node];
    int j = b0;
    for (; j + 4 <= b1; j += 4){
        int s0 = csr[j], s1 = csr[j + 1], s2 = csr[j + 2], s3 = csr[j + 3];
        uint4 u0 = Hin[s0 * 16 + c];
        uint4 u1 = Hin[s1 * 16 + c];
        uint4 u2 = Hin[s2 * 16 + c];
        uint4 u3 = Hin[s3 * 16 + c];
        acc8(a, u0); acc8(a, u1); acc8(a, u2); acc8(a, u3);
    }
    for (; j < b1; j++){
        int s = csr[j];
        uint4 u = Hin[s * 16 + c];
        acc8(a, u);
    }

    uint4 o;
    o.x = pack2(a[0], a[1]);
    o.y = pack2(a[2], a[3]);
    o.z = pack2(a[4], a[5]);
    o.w = pack2(a[6], a[7]);
    Hout[node * 16 + c] = o;
}

// ---------------- pooling: 64-row segments per wave, gmap precomputed, run-flush atomics ----------------

__global__ __launch_bounds__(256) void pool2_k(const u32* __restrict__ H,
                                               const int* __restrict__ gmap,
                                               float* __restrict__ out, int N){
    int c = threadIdx.x & 63;        // column pair: cols 2c, 2c+1
    int seg = blockIdx.x * 4 + (threadIdx.x >> 6);
    int start = seg * 64;
    if (start >= N) return;
    int end = start + 64; if (end > N) end = N;
    int g = gmap[start];
    float a0 = 0.f, a1 = 0.f;
    for (int n = start; n < end; n++){
        int gn = gmap[n];
        if (gn != g){
            unsafeAtomicAdd(&out[g * 128 + 2 * c], a0);
            unsafeAtomicAdd(&out[g * 128 + 2 * c + 1], a1);
            a0 = 0.f; a1 = 0.f; g = gn;
        }
        u32 u = H[n * 64 + c];
        a0 += bfl(u);
        a1 += bfh(u);
    }
    unsafeAtomicAdd(&out[g * 128 + 2 * c], a0);
    unsafeAtomicAdd(&out[g * 128 + 2 * c + 1], a1);
}

extern "C" void kernel_launch(void* const* d_in, const int* in_sizes, int n_in,
                              void* d_out, int out_size, void* d_ws, size_t ws_size,
                              hipStream_t stream){
    const float* x    = (const float*)d_in[0];
    const int*   ei   = (const int*)d_in[1];
    const int*   n2s  = (const int*)d_in[2];
    const int*   s2g  = (const int*)d_in[3];
    const float* c1W1 = (const float*)d_in[4];
    const float* c1b1 = (const float*)d_in[5];
    const float* c1W2 = (const float*)d_in[6];
    const float* c1b2 = (const float*)d_in[7];
    const float* cW1  = (const float*)d_in[8];
    const float* cb1  = (const float*)d_in[9];
    const float* cW2  = (const float*)d_in[10];
    const float* cb2  = (const float*)d_in[11];
    float* out = (float*)d_out;

    int N = in_sizes[0];          // 100000
    int E = in_sizes[1] / 2;      // 1600000
    const int* src = ei;
    const int* dst = ei + E;
    int NBk = (N + 127) / 128;    // 782 coarse buckets

    // ---- workspace layout ----
    char* w = (char*)d_ws;
    size_t off = 0;
    auto al = [&](size_t b){ size_t r = off; off += (b + 255) & ~(size_t)255; return r; };
    int*   gcur   = (int*)(w + al((size_t)NBk * 4));
    int*   starts = (int*)(w + al((size_t)N * 4));
    int*   ends   = (int*)(w + al((size_t)N * 4));
    float* sval   = (float*)(w + al((size_t)N * 4));
    int*   gmap   = (int*)(w + al((size_t)N * 4));
    u32*   csr    = (u32*)(w + al((size_t)NBk * CAP * 4));
    u16*   wp     = (u16*)(w + al((size_t)5 * 16384 * 2));
    u16*   P      = (u16*)(w + al((size_t)N * 128 * 2));
    u16*   Q      = (u16*)(w + al((size_t)N * 128 * 2));

    // pack 5 weight matrices; blocks 5/6 zero gcur and out
    W5 w5;
    w5.p[0] = c1W2;
    w5.p[1] = cW1;           // layer2 W1
    w5.p[2] = cW2;           // layer2 W2
    w5.p[3] = cW1 + 16384;   // layer3 W1
    w5.p[4] = cW2 + 16384;   // layer3 W2
    pack_k<<<7, 256, 0, stream>>>(w5, wp, gcur, NBk, out, out_size);

    // CSR build (+ fused sval/gmap)
    bucket_count<<<(E + CHUNK - 1) / CHUNK, 1024, 0, stream>>>(dst, src, gcur, csr, NBk, E);
    bucket_csr<<<NBk, 512, 0, stream>>>(gcur, csr, starts, ends, x, n2s, s2g, sval, gmap, N);

    int gG = (N + 64 * GMT - 1) / (64 * GMT);   // gemm blocks (128 rows each)
    int gA = (N * 16 + 255) / 256;              // agg blocks: 16 threads per node
    // layer 1 (fused: h=relu(sval*W1+b1) generated in-kernel, then @W2)
    gemm1_fused<<<gG, 256, 0, stream>>>(sval, c1W1, c1b1, wp + 0 * 16384, c1b2, P, N);
    // layer 2 (agg, then fused W1+W2 MLP)
    agg_k<<<gA, 256, 0, stream>>>((const uint4*)P, (uint4*)Q, starts, ends, csr, N);
    gemm2_fused<<<gG, 256, 0, stream>>>(Q, wp + 1 * 16384, wp + 2 * 16384, cb1, cb2, Q, N);
    // layer 3
    agg_k<<<gA, 256, 0, stream>>>((const uint4*)Q, (uint4*)P, starts, ends, csr, N);
    gemm2_fused<<<gG, 256, 0, stream>>>(P, wp + 3 * 16384, wp + 4 * 16384, cb1 + 128, cb2 + 128, P, N);
    // pooling
    pool2_k<<<(N + 255) / 256, 256, 0, stream>>>((const u32*)P, gmap, out, N);
}